// Round 16
// baseline (371.430 us; speedup 1.0000x reference)
//
#include <hip/hip_runtime.h>

#define NSLOPE 0.2f
#define CAP 128            // bucket capacity per dst node (max degree ~66 incl. self-loop)

typedef __bf16 bf16x8 __attribute__((ext_vector_type(8)));
typedef __bf16 bf16x4 __attribute__((ext_vector_type(4)));
typedef __bf16 bf16x2 __attribute__((ext_vector_type(2)));
typedef float  f32x4  __attribute__((ext_vector_type(4)));
typedef _Float16 half2v __attribute__((ext_vector_type(2)));

// fp16 pair dot with f32 accumulate: one v_dot2_f32_f16 when available.
static __device__ __forceinline__ float dot2f(unsigned p, unsigned a, float c){
#if __has_builtin(__builtin_amdgcn_fdot2)
  return __builtin_amdgcn_fdot2(__builtin_bit_cast(half2v, p),
                                __builtin_bit_cast(half2v, a), c, false);
#else
  half2v ph = __builtin_bit_cast(half2v, p), ah = __builtin_bit_cast(half2v, a);
  return c + (float)ph[0]*(float)ah[0] + (float)ph[1]*(float)ah[1];
#endif
}

// pack two f32 into f16x2 (v_cvt_pkrtz_f16_f32 when available)
static __device__ __forceinline__ unsigned pk2h(float a, float b){
#if __has_builtin(__builtin_amdgcn_cvt_pkrtz)
  return __builtin_bit_cast(unsigned, __builtin_amdgcn_cvt_pkrtz(a, b));
#else
  half2v h; h[0] = (_Float16)a; h[1] = (_Float16)b;
  return __builtin_bit_cast(unsigned, h);
#endif
}

// ============================================================================
// FRAME LAYOUT: matrix [R rows][K cols] bf16 stored as frames of 16 rows x
// 32 k. Frame (rb, kf) holds lane slot = (row&15) + 16*((k>>3)&3), elem k&7.
// Element addr (bf16 units) = rb*(K*16) + kf*512 + slot*8 + (k&7).
// K = 128 (layer 1) / 512 (layers 2,3); no hi|lo fold (R8-verified inert).
// R16: aggregate is serial-edge-latency bound (~22K cyc/wave = 16 pair-iters
// x ~500cyc unpipelined L2 latency; explains R10/R11/R12/R15 nulls). Fix:
// 4-way EDGE-parallel block (256 thr): each wave takes a <=32-edge quarter
// (serial depth /4), block-reduced softmax (2 barriers), shfl-broadcast
// src/alpha (no LDS in loop), LDS partial combine. GEMM/prep/fill R9-exact.
// ============================================================================

// ===== bucket fill: append edges after prep pre-inserted self-loops =========
__global__ void fill_kernel(const int* __restrict__ ei, int E,
                            int* cnt, int* __restrict__ col){
  int i = blockIdx.x*blockDim.x + threadIdx.x;
  if (i < E){
    int s = ei[i], d = ei[E + i];
    int slot = atomicAdd(&cnt[d], 1);
    if (slot < CAP) col[(d << 7) + slot] = s;   // CAP==128
  }
}

// ===== W [K][Nc] fp32 -> frame-layout bf16 B ================================
__device__ __forceinline__ void wsplit_body(
    const float* __restrict__ W, __bf16* __restrict__ Bt, int K, int Nc,
    int kb, int nb, float (*hi_s)[33]){
  int tx = threadIdx.x & 31, ty = threadIdx.x >> 5;   // 32 x 8
  int k0 = kb * 32, n0 = nb * 32;
#pragma unroll
  for (int i = 0; i < 4; i++){
    int r = ty + i*8;
    hi_s[r][tx] = (float)(__bf16)W[(size_t)(k0 + r)*Nc + n0 + tx];
  }
  __syncthreads();
  const size_t Kx16 = (size_t)K * 16;          // 16-row block stride
#pragma unroll
  for (int i = 0; i < 4; i++){
    int n = ty + i*8;
    int r = n0 + n;                            // B row = W col
    size_t a = (size_t)(r >> 4)*Kx16 + (size_t)(k0 >> 5)*512
             + (size_t)((r & 15) + 16*(tx >> 3))*8 + (tx & 7);
    Bt[a] = (__bf16)hi_s[tx][n];
  }
}

// ===== fused prep: cnt=1 + self-loop col + al zero + pack(x) + pack(W*) =====
__global__ __launch_bounds__(256) void prep_kernel(
    const float* __restrict__ x, __bf16* __restrict__ X2,
    const float* __restrict__ W1, __bf16* __restrict__ B1t,
    const float* __restrict__ W2, __bf16* __restrict__ B2t,
    const float* __restrict__ W3, __bf16* __restrict__ B3t,
    int* __restrict__ cnt, int* __restrict__ col,
    float* __restrict__ albase, int N){
  __shared__ float hi_s[32][33];
  int b = blockIdx.x, t = threadIdx.x;
  int gid = b*256 + t;
  if (gid < N){
    cnt[gid] = 1;                  // self-loop pre-count
    col[gid << 7] = gid;           // self-loop entry at slot 0
  }
  // zero al_s/al_d for all 3 layers: 18N floats contiguous, float4 stores
  if (gid*4 < N*18) *(float4*)(albase + gid*4) = make_float4(0.f,0.f,0.f,0.f);

  const int nb_split = (N*32 + 255) / 256;   // 1250
  if (b < nb_split){
    int i = gid * 4;
    if (i < N*128){
      int n = i >> 7, c = i & 127;           // 4 consecutive channels
      float4 v = *(const float4*)(x + i);
      float f[4] = {v.x, v.y, v.z, v.w};
      bf16x4 h;
#pragma unroll
      for (int u = 0; u < 4; u++) h[u] = (__bf16)f[u];
      // frame layout, K=128
      size_t a = (size_t)(n >> 4)*2048 + (size_t)(c >> 5)*512
               + (size_t)((n & 15) + 16*((c >> 3) & 3))*8 + (c & 7);
      *(bf16x4*)(X2 + a) = h;
    }
  } else if (b < nb_split + 64){
    int bb = b - nb_split;                   // W1: K=128 -> 4 x 16
    wsplit_body(W1, B1t, 128, 512, bb & 3, bb >> 2, hi_s);
  } else if (b < nb_split + 64 + 256){
    int bb = b - nb_split - 64;              // W2: 16 x 16
    wsplit_body(W2, B2t, 512, 512, bb & 15, bb >> 4, hi_s);
  } else {
    int bb = b - nb_split - 320;             // W3: 16 x 16
    wsplit_body(W3, B3t, 512, 512, bb & 15, bb >> 4, hi_s);
  }
}

// ========== bf16 MFMA GEMM, f16 output (R9-exact, BM=64) ====================
template<int H>
__global__ __launch_bounds__(256) void gemm_mfma(
    const __bf16* __restrict__ A2f, const __bf16* __restrict__ B2f,
    _Float16* __restrict__ Hb, const float* __restrict__ asrc,
    const float* __restrict__ adst, float* __restrict__ al_s,
    float* __restrict__ al_d, int M, int K2){
  int t = threadIdx.x, w = t >> 6, lane = t & 63;
  int mm = lane & 15, q = lane >> 4;

  int bid = blockIdx.x;
  int idx = bid >> 3;
  int cb = idx & 3;
  int rowblk = (bid & 7) + ((idx >> 2) << 3);   // xcd-pinned row panels
  if (rowblk * 64 >= M) return;
  int bm = rowblk * 64, bn = cb * 128;
  int wr = w & 1, wc = w >> 1;

  const int nf = K2 >> 5;                 // frames per row-block
  const int rbmax = (M >> 4) - 1;
  const __bf16* pA0; const __bf16* pA1;
  const __bf16* pB0; const __bf16* pB1; const __bf16* pB2; const __bf16* pB3;
  {
    int rb0 = (bm >> 4) + wr*2;     rb0 = (rb0 <= rbmax) ? rb0 : rbmax;
    int rb1 = (bm >> 4) + wr*2 + 1; rb1 = (rb1 <= rbmax) ? rb1 : rbmax;
    pA0 = A2f + (size_t)rb0*nf*512 + lane*8;
    pA1 = A2f + (size_t)rb1*nf*512 + lane*8;
    int rbB = (bn >> 4) + wc*4;
    pB0 = B2f + (size_t)(rbB+0)*nf*512 + lane*8;
    pB1 = B2f + (size_t)(rbB+1)*nf*512 + lane*8;
    pB2 = B2f + (size_t)(rbB+2)*nf*512 + lane*8;
    pB3 = B2f + (size_t)(rbB+3)*nf*512 + lane*8;
  }

  f32x4 acc[2][4];
#pragma unroll
  for (int i = 0; i < 2; i++)
#pragma unroll
    for (int j = 0; j < 4; j++)
#pragma unroll
      for (int r = 0; r < 4; r++) acc[i][j][r] = 0.f;

#pragma unroll 4
  for (int f = 0; f < nf; f++){
    bf16x8 a0 = *(const bf16x8*)(pA0 + (size_t)f*512);
    bf16x8 a1 = *(const bf16x8*)(pA1 + (size_t)f*512);
    bf16x8 b0 = *(const bf16x8*)(pB0 + (size_t)f*512);
    bf16x8 b1 = *(const bf16x8*)(pB1 + (size_t)f*512);
    bf16x8 b2 = *(const bf16x8*)(pB2 + (size_t)f*512);
    bf16x8 b3 = *(const bf16x8*)(pB3 + (size_t)f*512);
    acc[0][0] = __builtin_amdgcn_mfma_f32_16x16x32_bf16(a0, b0, acc[0][0], 0, 0, 0);
    acc[0][1] = __builtin_amdgcn_mfma_f32_16x16x32_bf16(a0, b1, acc[0][1], 0, 0, 0);
    acc[0][2] = __builtin_amdgcn_mfma_f32_16x16x32_bf16(a0, b2, acc[0][2], 0, 0, 0);
    acc[0][3] = __builtin_amdgcn_mfma_f32_16x16x32_bf16(a0, b3, acc[0][3], 0, 0, 0);
    acc[1][0] = __builtin_amdgcn_mfma_f32_16x16x32_bf16(a1, b0, acc[1][0], 0, 0, 0);
    acc[1][1] = __builtin_amdgcn_mfma_f32_16x16x32_bf16(a1, b1, acc[1][1], 0, 0, 0);
    acc[1][2] = __builtin_amdgcn_mfma_f32_16x16x32_bf16(a1, b2, acc[1][2], 0, 0, 0);
    acc[1][3] = __builtin_amdgcn_mfma_f32_16x16x32_bf16(a1, b3, acc[1][3], 0, 0, 0);
  }

  // ---- epilogue: Hb store (f16) + fused attention dots -----------------
  float as_v[4], ad_v[4];
#pragma unroll
  for (int j2 = 0; j2 < 4; j2++){
    int colc = bn + (wc*4 + j2)*16 + mm;
    as_v[j2] = asrc[colc];
    ad_v[j2] = adst[colc];
  }
  const int h = (H == 4) ? (bn >> 7) : 0;
#pragma unroll
  for (int i2 = 0; i2 < 2; i2++){
    int rbase = bm + (wr*2 + i2)*16 + q*4;
#pragma unroll
    for (int j2 = 0; j2 < 4; j2++){
      int colc = bn + (wc*4 + j2)*16 + mm;
#pragma unroll
      for (int r = 0; r < 4; r++){
        int row = rbase + r;
        if (row < M) Hb[(size_t)row*512 + colc] = (_Float16)acc[i2][j2][r];
      }
    }
#pragma unroll
    for (int r = 0; r < 4; r++){
      float ps = acc[i2][0][r]*as_v[0] + acc[i2][1][r]*as_v[1]
               + acc[i2][2][r]*as_v[2] + acc[i2][3][r]*as_v[3];
      float pd = acc[i2][0][r]*ad_v[0] + acc[i2][1][r]*ad_v[1]
               + acc[i2][2][r]*ad_v[2] + acc[i2][3][r]*ad_v[3];
#pragma unroll
      for (int off = 1; off < 16; off <<= 1){
        ps += __shfl_xor(ps, off);
        pd += __shfl_xor(pd, off);
      }
      int row = rbase + r;
      if (mm == 0 && row < M){
        atomicAdd(&al_s[(size_t)row*H + h], ps);
        atomicAdd(&al_d[(size_t)row*H + h], pd);
      }
    }
  }
}

// ====== edge-parallel gather: 256 thr = 4 waves, each a <=32-edge quarter ===
// Block handles (node d, 128-ch slice s) with R9's XCD mapping (x = g&7).
// Wave w processes edges [w*qlen, +qcnt): serial depth ~deg/8 pair-iters
// (was ~deg/2). Softmax via 2-barrier block reduction; src/alpha broadcast
// from loading lanes via shfl (no LDS in the MAC loop); partials combined
// in LDS by wave 0.
template<int H, int MODE>
__global__ __launch_bounds__(256) void aggregate_slice(
    const _Float16* __restrict__ Hb, const float* __restrict__ al_s,
    const float* __restrict__ al_d, const int* __restrict__ cnt,
    const int* __restrict__ col, const float* __restrict__ bias,
    float* __restrict__ outF, __bf16* __restrict__ fA,
    int nidx, int N){
  __shared__ float red[8];
  __shared__ float partx[4][64], party[4][64];
  int g = blockIdx.x;
  int x = g & 7, idx = g >> 3;
  int s = x >> 1, half = x & 1;
  int d = half * nidx + idx;
  if (d >= N) return;                      // uniform across block
  int t = threadIdx.x, w = t >> 6, lane = t & 63;
  const int hh = (H == 1) ? 0 : s;
  const float ald = al_d[(size_t)d*H + hh];
  int deg = cnt[d]; deg = (deg < CAP) ? deg : CAP;
  int start = d << 7;
  int qlen = (deg + 3) >> 2;               // <= 32
  int qbeg = w * qlen;
  int qcnt = deg - qbeg;
  qcnt = (qcnt < 0) ? 0 : ((qcnt < qlen) ? qcnt : qlen);

  // load this quarter's cols + logits (lane < qcnt <= 32)
  int sc = 0; float vf = -1e30f;
  if (lane < qcnt){
    sc = col[start + qbeg + lane];
    float v = al_s[(size_t)sc*H + hh] + ald;
    vf = (v > 0.f) ? v : NSLOPE * v;
  }
  // block max
  float mx = vf;
#pragma unroll
  for (int off = 32; off > 0; off >>= 1)
    mx = fmaxf(mx, __shfl_xor(mx, off));
  if (lane == 0) red[w] = mx;
  __syncthreads();
  mx = fmaxf(fmaxf(red[0], red[1]), fmaxf(red[2], red[3]));
  // block sum of exp
  float e = (lane < qcnt) ? __expf(vf - mx) : 0.f;
  float ss = e;
#pragma unroll
  for (int off = 32; off > 0; off >>= 1)
    ss += __shfl_xor(ss, off);
  if (lane == 0) red[4 + w] = ss;
  __syncthreads();
  float lsum = (red[4] + red[5]) + (red[6] + red[7]);

  const unsigned* __restrict__ Hb32 = (const unsigned*)Hb;   // row = 256 u32
  const unsigned coffu = s*64 + lane;                        // channel pair idx
  float accx = 0.f, accy = 0.f;

  int npc = (qcnt + 1) >> 1;               // pair count (ceil); lanes 2*npc-1 < 64
  int j = 0;
  for (; j + 2 <= npc; j += 2){
    int s0 = __shfl(sc, 2*j),   s1 = __shfl(sc, 2*j+1);
    int s2 = __shfl(sc, 2*j+2), s3 = __shfl(sc, 2*j+3);
    float f0 = __shfl(e, 2*j),   f1 = __shfl(e, 2*j+1);
    float f2 = __shfl(e, 2*j+2), f3 = __shfl(e, 2*j+3);
    unsigned u0 = Hb32[(size_t)s0*256 + coffu];
    unsigned u1 = Hb32[(size_t)s1*256 + coffu];
    unsigned u2 = Hb32[(size_t)s2*256 + coffu];
    unsigned u3 = Hb32[(size_t)s3*256 + coffu];
    unsigned a01 = pk2h(f0, f1);
    unsigned a23 = pk2h(f2, f3);
    unsigned pc  = (u0 & 0x0000ffffu) | (u1 << 16);
    unsigned pc1 = (u0 >> 16) | (u1 & 0xffff0000u);
    unsigned qc  = (u2 & 0x0000ffffu) | (u3 << 16);
    unsigned qc1 = (u2 >> 16) | (u3 & 0xffff0000u);
    accx = dot2f(pc,  a01, accx);
    accy = dot2f(pc1, a01, accy);
    accx = dot2f(qc,  a23, accx);
    accy = dot2f(qc1, a23, accy);
  }
  for (; j < npc; j++){
    int s0 = __shfl(sc, 2*j), s1 = __shfl(sc, 2*j+1);   // e beyond qcnt is 0
    float f0 = __shfl(e, 2*j), f1 = __shfl(e, 2*j+1);
    unsigned u0 = Hb32[(size_t)s0*256 + coffu];
    unsigned u1 = Hb32[(size_t)s1*256 + coffu];
    unsigned a01 = pk2h(f0, f1);
    unsigned pc  = (u0 & 0x0000ffffu) | (u1 << 16);
    unsigned pc1 = (u0 >> 16) | (u1 & 0xffff0000u);
    accx = dot2f(pc,  a01, accx);
    accy = dot2f(pc1, a01, accy);
  }

  partx[w][lane] = accx;
  party[w][lane] = accy;
  __syncthreads();
  if (w == 0){
    float ax = (partx[0][lane] + partx[1][lane])
             + (partx[2][lane] + partx[3][lane]);
    float ay = (party[0][lane] + party[1][lane])
             + (party[2][lane] + party[3][lane]);
    float invd = 1.f / lsum;
    int c = s*128 + lane*2;
    float2 bv = *(const float2*)(bias + c);
    float r0 = ax * invd + bv.x;
    float r1 = ay * invd + bv.y;
    if (MODE == 1){
      r0 = fmaxf(r0, 0.f); r1 = fmaxf(r1, 0.f);
      bf16x2 hv; hv[0] = (__bf16)r0; hv[1] = (__bf16)r1;
      // frame layout write (K=512): rb stride 512*16 = 8192
      size_t a = (size_t)(d >> 4)*8192 + (size_t)(c >> 5)*512
               + (size_t)((d & 15) + 16*((c >> 3) & 3))*8 + (c & 7);
      *(bf16x2*)(fA + a) = hv;
    } else {
      *(float2*)(outF + (size_t)d*512 + c) = make_float2(r0, r1);
    }
  }
}

// =========================== launch =========================================
extern "C" void kernel_launch(void* const* d_in, const int* in_sizes, int n_in,
                              void* d_out, int out_size, void* d_ws, size_t ws_size,
                              hipStream_t stream){
  const float* x   = (const float*)d_in[0];
  const int*   ei  = (const int*)  d_in[1];
  const float* W1  = (const float*)d_in[2];
  const float* as1 = (const float*)d_in[3];
  const float* ad1 = (const float*)d_in[4];
  const float* b1  = (const float*)d_in[5];
  const float* W2  = (const float*)d_in[6];
  const float* as2 = (const float*)d_in[7];
  const float* ad2 = (const float*)d_in[8];
  const float* b2  = (const float*)d_in[9];
  const float* W3  = (const float*)d_in[10];
  const float* as3 = (const float*)d_in[11];
  const float* ad3 = (const float*)d_in[12];
  const float* b3  = (const float*)d_in[13];
  float* out = (float*)d_out;

  const int N = in_sizes[0] / 128;   // 10000
  const int E = in_sizes[1] / 2;     // 320000
  const int nidx = (N + 1) / 2;

  // workspace carve-up
  __bf16* feat2  = (__bf16*)d_ws;                     // N*512 bf16 (frame)
  __bf16* X2     = feat2 + (size_t)N*512;             // N*128 bf16 (frame, layer-1 A)
  float*  albase = (float*)(X2 + (size_t)N*128);      // 18*N floats total:
  float*  als1   = albase;                            //  N*4
  float*  ald1   = als1 + (size_t)N*4;                //  N*4
  float*  als2   = ald1 + (size_t)N*4;                //  N*4
  float*  ald2   = als2 + (size_t)N*4;                //  N*4
  float*  als3   = ald2 + (size_t)N*4;                //  N
  float*  ald3   = als3 + (size_t)N;                  //  N
  int*    cnt    = (int*)(ald3 + (size_t)N);          // N
  int*    col    = cnt + N;                           // N*CAP
  uintptr_t p  = (uintptr_t)(col + (size_t)N*CAP);
  p = (p + 15) & ~(uintptr_t)15;
  __bf16* B1t = (__bf16*)p;                           // 512*128 bf16 (frame)
  __bf16* B2t = B1t + 512*128;                        // 512*512 bf16 (frame)
  __bf16* B3t = B2t + 512*512;                        // 512*512 bf16 (frame)
  _Float16* Hb = (_Float16*)(B3t + 512*512);          // N*512 f16 (row-major, gather)

  const int nb_split = (N*32 + 255)/256;              // 1250
  const int pgrid = nb_split + 64 + 256 + 256;        // 1826

  // prep: cnt=1 + self-loop col + al-zero, pack x, pack W1/W2/W3
  prep_kernel<<<pgrid, 256, 0, stream>>>(x, X2, W1, B1t, W2, B2t, W3, B3t,
                                         cnt, col, albase, N);
  fill_kernel<<<(E+255)/256, 256, 0, stream>>>(ei, E, cnt, col);

  const int nrb = (N + 63)/64;                        // 157 row panels (BM=64)
  const int ggrid = (((nrb + 7) >> 3) << 3) * 4;      // 160*4 = 640 (XCD map)
  const int agrid = nidx * 8;                         // 40000 blocks x 256 thr

  // ---- layer 1: x[N,128] @ W1[128,512]  (K = 128) ----
  gemm_mfma<4><<<ggrid, 256, 0, stream>>>(X2, B1t, Hb, as1, ad1, als1, ald1, N, 128);
  aggregate_slice<4,1><<<agrid, 256, 0, stream>>>(Hb, als1, ald1, cnt, col, b1,
      (float*)nullptr, feat2, nidx, N);

  // ---- layer 2: feat[N,512] @ W2[512,512]  (K = 512) ----
  gemm_mfma<4><<<ggrid, 256, 0, stream>>>(feat2, B2t, Hb, as2, ad2, als2, ald2, N, 512);
  aggregate_slice<4,1><<<agrid, 256, 0, stream>>>(Hb, als2, ald2, cnt, col, b2,
      (float*)nullptr, feat2, nidx, N);

  // ---- layer 3: feat[N,512] @ W3[512,512], heads=1  (K = 512) ----
  gemm_mfma<1><<<ggrid, 256, 0, stream>>>(feat2, B3t, Hb, as3, ad3, als3, ald3, N, 512);
  aggregate_slice<1,0><<<agrid, 256, 0, stream>>>(Hb, als3, ald3, cnt, col, b3,
      out, (__bf16*)nullptr, nidx, N);
}

// Round 17
// 269.492 us; speedup vs baseline: 1.3783x; 1.3783x over previous
//
#include <hip/hip_runtime.h>

#define NSLOPE 0.2f
#define CAP 128            // bucket capacity per dst node (max degree ~66 incl. self-loop)

typedef __bf16 bf16x8 __attribute__((ext_vector_type(8)));
typedef __bf16 bf16x4 __attribute__((ext_vector_type(4)));
typedef __bf16 bf16x2 __attribute__((ext_vector_type(2)));
typedef float  f32x4  __attribute__((ext_vector_type(4)));
typedef _Float16 half2v __attribute__((ext_vector_type(2)));

// fp16 pair dot with f32 accumulate: one v_dot2_f32_f16 when available.
static __device__ __forceinline__ float dot2f(unsigned p, unsigned a, float c){
#if __has_builtin(__builtin_amdgcn_fdot2)
  return __builtin_amdgcn_fdot2(__builtin_bit_cast(half2v, p),
                                __builtin_bit_cast(half2v, a), c, false);
#else
  half2v ph = __builtin_bit_cast(half2v, p), ah = __builtin_bit_cast(half2v, a);
  return c + (float)ph[0]*(float)ah[0] + (float)ph[1]*(float)ah[1];
#endif
}

// one-instruction byte-permute pack (v_perm_b32): replaces 2 bitops.
// lo16(u0)|lo16(u1)<<16  -> perm(a=u1,b=u0, 0x05040100)
// hi16(u0)|hi16(u1)      -> perm(a=u1,b=u0, 0x07060302)
static __device__ __forceinline__ unsigned permlo(unsigned u0, unsigned u1){
#if __has_builtin(__builtin_amdgcn_perm)
  return __builtin_amdgcn_perm(u1, u0, 0x05040100u);
#else
  return (u0 & 0x0000ffffu) | (u1 << 16);
#endif
}
static __device__ __forceinline__ unsigned permhi(unsigned u0, unsigned u1){
#if __has_builtin(__builtin_amdgcn_perm)
  return __builtin_amdgcn_perm(u1, u0, 0x07060302u);
#else
  return (u0 >> 16) | (u1 & 0xffff0000u);
#endif
}

// ============================================================================
// FRAME LAYOUT: matrix [R rows][K cols] bf16 stored as frames of 16 rows x
// 32 k. Frame (rb, kf) holds lane slot = (row&15) + 16*((k>>3)&3), elem k&7.
// Element addr (bf16 units) = rb*(K*16) + kf*512 + slot*8 + (k&7).
// K = 128 (layer 1) / 512 (layers 2,3); no hi|lo fold (R8-verified inert).
// R17: R9-exact structure (best, 266.9us). Single change: f16-pair packing
// in the aggregate hot loop via v_perm_b32 (1 instr) instead of 2 bitops.
// Model (R15/R16 evidence): aggregate is VALU-issue-bound at 50-65% given
// the 2.5MB/XCD Hb slice stays L2-resident; only instruction-count cuts
// that preserve the slice mapping can help.
// ============================================================================

// ===== bucket fill: append edges after prep pre-inserted self-loops =========
__global__ void fill_kernel(const int* __restrict__ ei, int E,
                            int* cnt, int* __restrict__ col){
  int i = blockIdx.x*blockDim.x + threadIdx.x;
  if (i < E){
    int s = ei[i], d = ei[E + i];
    int slot = atomicAdd(&cnt[d], 1);
    if (slot < CAP) col[(d << 7) + slot] = s;   // CAP==128
  }
}

// ===== W [K][Nc] fp32 -> frame-layout bf16 B ================================
__device__ __forceinline__ void wsplit_body(
    const float* __restrict__ W, __bf16* __restrict__ Bt, int K, int Nc,
    int kb, int nb, float (*hi_s)[33]){
  int tx = threadIdx.x & 31, ty = threadIdx.x >> 5;   // 32 x 8
  int k0 = kb * 32, n0 = nb * 32;
#pragma unroll
  for (int i = 0; i < 4; i++){
    int r = ty + i*8;
    hi_s[r][tx] = (float)(__bf16)W[(size_t)(k0 + r)*Nc + n0 + tx];
  }
  __syncthreads();
  const size_t Kx16 = (size_t)K * 16;          // 16-row block stride
#pragma unroll
  for (int i = 0; i < 4; i++){
    int n = ty + i*8;
    int r = n0 + n;                            // B row = W col
    size_t a = (size_t)(r >> 4)*Kx16 + (size_t)(k0 >> 5)*512
             + (size_t)((r & 15) + 16*(tx >> 3))*8 + (tx & 7);
    Bt[a] = (__bf16)hi_s[tx][n];
  }
}

// ===== fused prep: cnt=1 + self-loop col + al zero + pack(x) + pack(W*) =====
__global__ __launch_bounds__(256) void prep_kernel(
    const float* __restrict__ x, __bf16* __restrict__ X2,
    const float* __restrict__ W1, __bf16* __restrict__ B1t,
    const float* __restrict__ W2, __bf16* __restrict__ B2t,
    const float* __restrict__ W3, __bf16* __restrict__ B3t,
    int* __restrict__ cnt, int* __restrict__ col,
    float* __restrict__ albase, int N){
  __shared__ float hi_s[32][33];
  int b = blockIdx.x, t = threadIdx.x;
  int gid = b*256 + t;
  if (gid < N){
    cnt[gid] = 1;                  // self-loop pre-count
    col[gid << 7] = gid;           // self-loop entry at slot 0
  }
  // zero al_s/al_d for all 3 layers: 18N floats contiguous, float4 stores
  if (gid*4 < N*18) *(float4*)(albase + gid*4) = make_float4(0.f,0.f,0.f,0.f);

  const int nb_split = (N*32 + 255) / 256;   // 1250
  if (b < nb_split){
    int i = gid * 4;
    if (i < N*128){
      int n = i >> 7, c = i & 127;           // 4 consecutive channels
      float4 v = *(const float4*)(x + i);
      float f[4] = {v.x, v.y, v.z, v.w};
      bf16x4 h;
#pragma unroll
      for (int u = 0; u < 4; u++) h[u] = (__bf16)f[u];
      // frame layout, K=128
      size_t a = (size_t)(n >> 4)*2048 + (size_t)(c >> 5)*512
               + (size_t)((n & 15) + 16*((c >> 3) & 3))*8 + (c & 7);
      *(bf16x4*)(X2 + a) = h;
    }
  } else if (b < nb_split + 64){
    int bb = b - nb_split;                   // W1: K=128 -> 4 x 16
    wsplit_body(W1, B1t, 128, 512, bb & 3, bb >> 2, hi_s);
  } else if (b < nb_split + 64 + 256){
    int bb = b - nb_split - 64;              // W2: 16 x 16
    wsplit_body(W2, B2t, 512, 512, bb & 15, bb >> 4, hi_s);
  } else {
    int bb = b - nb_split - 320;             // W3: 16 x 16
    wsplit_body(W3, B3t, 512, 512, bb & 15, bb >> 4, hi_s);
  }
}

// ========== bf16 MFMA GEMM, f16 output (R9-exact, BM=64) ====================
template<int H>
__global__ __launch_bounds__(256) void gemm_mfma(
    const __bf16* __restrict__ A2f, const __bf16* __restrict__ B2f,
    _Float16* __restrict__ Hb, const float* __restrict__ asrc,
    const float* __restrict__ adst, float* __restrict__ al_s,
    float* __restrict__ al_d, int M, int K2){
  int t = threadIdx.x, w = t >> 6, lane = t & 63;
  int mm = lane & 15, q = lane >> 4;

  int bid = blockIdx.x;
  int idx = bid >> 3;
  int cb = idx & 3;
  int rowblk = (bid & 7) + ((idx >> 2) << 3);   // xcd-pinned row panels
  if (rowblk * 64 >= M) return;
  int bm = rowblk * 64, bn = cb * 128;
  int wr = w & 1, wc = w >> 1;

  const int nf = K2 >> 5;                 // frames per row-block
  const int rbmax = (M >> 4) - 1;
  const __bf16* pA0; const __bf16* pA1;
  const __bf16* pB0; const __bf16* pB1; const __bf16* pB2; const __bf16* pB3;
  {
    int rb0 = (bm >> 4) + wr*2;     rb0 = (rb0 <= rbmax) ? rb0 : rbmax;
    int rb1 = (bm >> 4) + wr*2 + 1; rb1 = (rb1 <= rbmax) ? rb1 : rbmax;
    pA0 = A2f + (size_t)rb0*nf*512 + lane*8;
    pA1 = A2f + (size_t)rb1*nf*512 + lane*8;
    int rbB = (bn >> 4) + wc*4;
    pB0 = B2f + (size_t)(rbB+0)*nf*512 + lane*8;
    pB1 = B2f + (size_t)(rbB+1)*nf*512 + lane*8;
    pB2 = B2f + (size_t)(rbB+2)*nf*512 + lane*8;
    pB3 = B2f + (size_t)(rbB+3)*nf*512 + lane*8;
  }

  f32x4 acc[2][4];
#pragma unroll
  for (int i = 0; i < 2; i++)
#pragma unroll
    for (int j = 0; j < 4; j++)
#pragma unroll
      for (int r = 0; r < 4; r++) acc[i][j][r] = 0.f;

#pragma unroll 4
  for (int f = 0; f < nf; f++){
    bf16x8 a0 = *(const bf16x8*)(pA0 + (size_t)f*512);
    bf16x8 a1 = *(const bf16x8*)(pA1 + (size_t)f*512);
    bf16x8 b0 = *(const bf16x8*)(pB0 + (size_t)f*512);
    bf16x8 b1 = *(const bf16x8*)(pB1 + (size_t)f*512);
    bf16x8 b2 = *(const bf16x8*)(pB2 + (size_t)f*512);
    bf16x8 b3 = *(const bf16x8*)(pB3 + (size_t)f*512);
    acc[0][0] = __builtin_amdgcn_mfma_f32_16x16x32_bf16(a0, b0, acc[0][0], 0, 0, 0);
    acc[0][1] = __builtin_amdgcn_mfma_f32_16x16x32_bf16(a0, b1, acc[0][1], 0, 0, 0);
    acc[0][2] = __builtin_amdgcn_mfma_f32_16x16x32_bf16(a0, b2, acc[0][2], 0, 0, 0);
    acc[0][3] = __builtin_amdgcn_mfma_f32_16x16x32_bf16(a0, b3, acc[0][3], 0, 0, 0);
    acc[1][0] = __builtin_amdgcn_mfma_f32_16x16x32_bf16(a1, b0, acc[1][0], 0, 0, 0);
    acc[1][1] = __builtin_amdgcn_mfma_f32_16x16x32_bf16(a1, b1, acc[1][1], 0, 0, 0);
    acc[1][2] = __builtin_amdgcn_mfma_f32_16x16x32_bf16(a1, b2, acc[1][2], 0, 0, 0);
    acc[1][3] = __builtin_amdgcn_mfma_f32_16x16x32_bf16(a1, b3, acc[1][3], 0, 0, 0);
  }

  // ---- epilogue: Hb store (f16) + fused attention dots -----------------
  float as_v[4], ad_v[4];
#pragma unroll
  for (int j2 = 0; j2 < 4; j2++){
    int colc = bn + (wc*4 + j2)*16 + mm;
    as_v[j2] = asrc[colc];
    ad_v[j2] = adst[colc];
  }
  const int h = (H == 4) ? (bn >> 7) : 0;
#pragma unroll
  for (int i2 = 0; i2 < 2; i2++){
    int rbase = bm + (wr*2 + i2)*16 + q*4;
#pragma unroll
    for (int j2 = 0; j2 < 4; j2++){
      int colc = bn + (wc*4 + j2)*16 + mm;
#pragma unroll
      for (int r = 0; r < 4; r++){
        int row = rbase + r;
        if (row < M) Hb[(size_t)row*512 + colc] = (_Float16)acc[i2][j2][r];
      }
    }
#pragma unroll
    for (int r = 0; r < 4; r++){
      float ps = acc[i2][0][r]*as_v[0] + acc[i2][1][r]*as_v[1]
               + acc[i2][2][r]*as_v[2] + acc[i2][3][r]*as_v[3];
      float pd = acc[i2][0][r]*ad_v[0] + acc[i2][1][r]*ad_v[1]
               + acc[i2][2][r]*ad_v[2] + acc[i2][3][r]*ad_v[3];
#pragma unroll
      for (int off = 1; off < 16; off <<= 1){
        ps += __shfl_xor(ps, off);
        pd += __shfl_xor(pd, off);
      }
      int row = rbase + r;
      if (mm == 0 && row < M){
        atomicAdd(&al_s[(size_t)row*H + h], ps);
        atomicAdd(&al_d[(size_t)row*H + h], pd);
      }
    }
  }
}

// ====== channel-sliced gather, XCD-pinned, dot2 inner loop (R9 + v_perm) ====
template<int H, int MODE>
__global__ __launch_bounds__(64) void aggregate_slice(
    const _Float16* __restrict__ Hb, const float* __restrict__ al_s,
    const float* __restrict__ al_d, const int* __restrict__ cnt,
    const int* __restrict__ col, const float* __restrict__ bias,
    float* __restrict__ outF, __bf16* __restrict__ fA,
    int nidx, int N){
  __shared__ int      src_s[64];
  __shared__ _Float16 a_sh[64];
  int g = blockIdx.x;
  int x = g & 7, idx = g >> 3;
  int s = x >> 1, half = x & 1;
  int d = half * nidx + idx;
  if (d >= N) return;
  int lane = threadIdx.x;
  const int hh = (H == 1) ? 0 : s;
  const float ald = al_d[(size_t)d*H + hh];
  int deg = cnt[d]; deg = (deg < CAP) ? deg : CAP;
  int start = d << 7;

  // gather logits once (<= 2 chunks), keep in registers
  int sc0 = 0, sc1 = 0;
  float v0f = -1e30f, v1f = -1e30f;
  if (lane < deg){
    sc0 = col[start + lane];
    float v = al_s[(size_t)sc0*H + hh] + ald;
    v0f = (v > 0.f) ? v : NSLOPE * v;
  }
  if (64 + lane < deg){
    sc1 = col[start + 64 + lane];
    float v = al_s[(size_t)sc1*H + hh] + ald;
    v1f = (v > 0.f) ? v : NSLOPE * v;
  }
  float mx = fmaxf(v0f, v1f);
#pragma unroll
  for (int off = 32; off > 0; off >>= 1)
    mx = fmaxf(mx, __shfl_xor(mx, off));

  float e0 = (lane < deg)      ? __expf(v0f - mx) : 0.f;
  float e1 = (64 + lane < deg) ? __expf(v1f - mx) : 0.f;
  float lsum = e0 + e1;
#pragma unroll
  for (int off = 32; off > 0; off >>= 1)
    lsum += __shfl_xor(lsum, off);

  const unsigned* __restrict__ Hb32 = (const unsigned*)Hb;   // row = 256 u32
  const unsigned coffu = s*64 + lane;                        // channel pair idx
  float accx = 0.f, accy = 0.f;

  int cc0 = (deg < 64) ? deg : 64;       // chunk A count
  src_s[lane] = sc0;
  a_sh[lane]  = (_Float16)e0;
  for (int chunk = 0; ; chunk++){
    int cnt2 = (chunk == 0) ? cc0 : (deg - 64);
    int npair = cnt2 >> 1;
    int j = 0;
    for (; j + 2 <= npair; j += 2){
      int s0 = src_s[2*j],     s1 = src_s[2*j+1];
      int s2 = src_s[2*j+2],   s3 = src_s[2*j+3];
      unsigned a01 = *(const unsigned*)&a_sh[2*j];
      unsigned a23 = *(const unsigned*)&a_sh[2*j+2];
      unsigned u0 = Hb32[(size_t)s0*256 + coffu];
      unsigned u1 = Hb32[(size_t)s1*256 + coffu];
      unsigned u2 = Hb32[(size_t)s2*256 + coffu];
      unsigned u3 = Hb32[(size_t)s3*256 + coffu];
      unsigned pc  = permlo(u0, u1);   // (e0_c , e1_c )
      unsigned pc1 = permhi(u0, u1);   // (e0_c1, e1_c1)
      unsigned qc  = permlo(u2, u3);
      unsigned qc1 = permhi(u2, u3);
      accx = dot2f(pc,  a01, accx);
      accy = dot2f(pc1, a01, accy);
      accx = dot2f(qc,  a23, accx);
      accy = dot2f(qc1, a23, accy);
    }
    for (; j < npair; j++){
      int s0 = src_s[2*j], s1 = src_s[2*j+1];
      unsigned a01 = *(const unsigned*)&a_sh[2*j];
      unsigned u0 = Hb32[(size_t)s0*256 + coffu];
      unsigned u1 = Hb32[(size_t)s1*256 + coffu];
      unsigned pc  = permlo(u0, u1);
      unsigned pc1 = permhi(u0, u1);
      accx = dot2f(pc,  a01, accx);
      accy = dot2f(pc1, a01, accy);
    }
    if (cnt2 & 1){
      int sl = src_s[cnt2 - 1];
      float al = (float)a_sh[cnt2 - 1];
      unsigned ul = Hb32[(size_t)sl*256 + coffu];
      half2v hv = __builtin_bit_cast(half2v, ul);
      accx += al * (float)hv[0];
      accy += al * (float)hv[1];
    }
    if (chunk == 1 || deg <= 64) break;
    // lockstep wave, in-order DS ops: chunk-A reads precede this overwrite
    src_s[lane] = sc1;
    a_sh[lane]  = (_Float16)e1;
  }

  float invd = 1.f / lsum;
  int c = s*128 + lane*2;
  float2 bv = *(const float2*)(bias + c);
  float r0 = accx * invd + bv.x;
  float r1 = accy * invd + bv.y;
  if (MODE == 1){
    r0 = fmaxf(r0, 0.f); r1 = fmaxf(r1, 0.f);
    bf16x2 hv; hv[0] = (__bf16)r0; hv[1] = (__bf16)r1;
    // frame layout write (K=512): rb stride 512*16 = 8192
    size_t a = (size_t)(d >> 4)*8192 + (size_t)(c >> 5)*512
             + (size_t)((d & 15) + 16*((c >> 3) & 3))*8 + (c & 7);
    *(bf16x2*)(fA + a) = hv;
  } else {
    *(float2*)(outF + (size_t)d*512 + c) = make_float2(r0, r1);
  }
}

// =========================== launch =========================================
extern "C" void kernel_launch(void* const* d_in, const int* in_sizes, int n_in,
                              void* d_out, int out_size, void* d_ws, size_t ws_size,
                              hipStream_t stream){
  const float* x   = (const float*)d_in[0];
  const int*   ei  = (const int*)  d_in[1];
  const float* W1  = (const float*)d_in[2];
  const float* as1 = (const float*)d_in[3];
  const float* ad1 = (const float*)d_in[4];
  const float* b1  = (const float*)d_in[5];
  const float* W2  = (const float*)d_in[6];
  const float* as2 = (const float*)d_in[7];
  const float* ad2 = (const float*)d_in[8];
  const float* b2  = (const float*)d_in[9];
  const float* W3  = (const float*)d_in[10];
  const float* as3 = (const float*)d_in[11];
  const float* ad3 = (const float*)d_in[12];
  const float* b3  = (const float*)d_in[13];
  float* out = (float*)d_out;

  const int N = in_sizes[0] / 128;   // 10000
  const int E = in_sizes[1] / 2;     // 320000
  const int nidx = (N + 1) / 2;

  // workspace carve-up
  __bf16* feat2  = (__bf16*)d_ws;                     // N*512 bf16 (frame)
  __bf16* X2     = feat2 + (size_t)N*512;             // N*128 bf16 (frame, layer-1 A)
  float*  albase = (float*)(X2 + (size_t)N*128);      // 18*N floats total:
  float*  als1   = albase;                            //  N*4
  float*  ald1   = als1 + (size_t)N*4;                //  N*4
  float*  als2   = ald1 + (size_t)N*4;                //  N*4
  float*  ald2   = als2 + (size_t)N*4;                //  N*4
  float*  als3   = ald2 + (size_t)N*4;                //  N
  float*  ald3   = als3 + (size_t)N;                  //  N
  int*    cnt    = (int*)(ald3 + (size_t)N);          // N
  int*    col    = cnt + N;                           // N*CAP
  uintptr_t p  = (uintptr_t)(col + (size_t)N*CAP);
  p = (p + 15) & ~(uintptr_t)15;
  __bf16* B1t = (__bf16*)p;                           // 512*128 bf16 (frame)
  __bf16* B2t = B1t + 512*128;                        // 512*512 bf16 (frame)
  __bf16* B3t = B2t + 512*512;                        // 512*512 bf16 (frame)
  _Float16* Hb = (_Float16*)(B3t + 512*512);          // N*512 f16 (row-major, gather)

  const int nb_split = (N*32 + 255)/256;              // 1250
  const int pgrid = nb_split + 64 + 256 + 256;        // 1826

  // prep: cnt=1 + self-loop col + al-zero, pack x, pack W1/W2/W3
  prep_kernel<<<pgrid, 256, 0, stream>>>(x, X2, W1, B1t, W2, B2t, W3, B3t,
                                         cnt, col, albase, N);
  fill_kernel<<<(E+255)/256, 256, 0, stream>>>(ei, E, cnt, col);

  const int nrb = (N + 63)/64;                        // 157 row panels (BM=64)
  const int ggrid = (((nrb + 7) >> 3) << 3) * 4;      // 160*4 = 640 (XCD map)
  const int agrid = nidx * 8;

  // ---- layer 1: x[N,128] @ W1[128,512]  (K = 128) ----
  gemm_mfma<4><<<ggrid, 256, 0, stream>>>(X2, B1t, Hb, as1, ad1, als1, ald1, N, 128);
  aggregate_slice<4,1><<<agrid, 64, 0, stream>>>(Hb, als1, ald1, cnt, col, b1,
      (float*)nullptr, feat2, nidx, N);

  // ---- layer 2: feat[N,512] @ W2[512,512]  (K = 512) ----
  gemm_mfma<4><<<ggrid, 256, 0, stream>>>(feat2, B2t, Hb, as2, ad2, als2, ald2, N, 512);
  aggregate_slice<4,1><<<agrid, 64, 0, stream>>>(Hb, als2, ald2, cnt, col, b2,
      (float*)nullptr, feat2, nidx, N);

  // ---- layer 3: feat[N,512] @ W3[512,512], heads=1  (K = 512) ----
  gemm_mfma<1><<<ggrid, 256, 0, stream>>>(feat2, B3t, Hb, as3, ad3, als3, ald3, N, 512);
  aggregate_slice<1,0><<<agrid, 64, 0, stream>>>(Hb, als3, ald3, cnt, col, b3,
      out, (__bf16*)nullptr, nidx, N);
}